// Round 7
// baseline (140.748 us; speedup 1.0000x reference)
//
#include <hip/hip_runtime.h>

#define LN_EPS 1e-5f

typedef _Float16 hv2 __attribute__((ext_vector_type(2)));

__device__ __forceinline__ float fast_rcp(float x) {
    return __builtin_amdgcn_rcpf(x);
}

__device__ __forceinline__ hv2 cvt2(float a, float b) {
    return __builtin_bit_cast(hv2, __builtin_amdgcn_cvt_pkrtz(a, b));   // v_cvt_pkrtz_f16_f32
}

__device__ __forceinline__ hv2 pkfma(hv2 a, hv2 b, hv2 c) {
    return __builtin_elementwise_fma(a, b, c);                          // v_pk_fma_f16
}

__device__ __forceinline__ float silu_f(float x) {
    return x * fast_rcp(1.0f + __expf(-x));
}

__device__ __forceinline__ float tanh_f(float x) {
    float t = __expf(-2.0f * x);
    float r = fast_rcp(1.0f + t);
    return fmaf(2.0f, r, -1.0f);
}

__device__ __forceinline__ float softplus_f(float x) {
    float e = __expf(-fabsf(x));
    return fmaxf(x, 0.0f) + __logf(1.0f + e);
}

// ---- d_ws layout (hv2 = neuron-pair packed, [K][N/2]) ----
// gw1p  [16][4]  @ 0     (64)
// gw2p  [8]      @ 64    (8)    pair = (logit0, logit1) per k
// gb1p  [4]      @ 72    (4)
// e1w1p [16][12] @ 76    (192)
// e1w2p [24][8]  @ 268   (192)
// e1b1p [12]     @ 460
// e1b2p [8]      @ 472
// e2w1p [16][12] @ 480   (192)
// e2w2p [24][8]  @ 672   (192)
// e2b1p [12]     @ 864
// e2b2p [8]      @ 876
// twp   [16][8]  @ 884   (128)
// tbp   [8]      @ 1012  -> total 1020

__global__ void pack_weights(const float* __restrict__ gw1, const float* __restrict__ gb1,
                             const float* __restrict__ gw2,
                             const float* __restrict__ e1w1, const float* __restrict__ e1b1,
                             const float* __restrict__ e1w2, const float* __restrict__ e1b2,
                             const float* __restrict__ e2w1, const float* __restrict__ e2b1,
                             const float* __restrict__ e2w2, const float* __restrict__ e2b2,
                             const float* __restrict__ tw, const float* __restrict__ tb,
                             hv2* __restrict__ ws) {
    int t = blockIdx.x * blockDim.x + threadIdx.x;
    if (t < 64) {                                     // gw1 (16,8)
        int k = t >> 2, j2 = t & 3;
        ws[t] = cvt2(gw1[k * 8 + 2 * j2], gw1[k * 8 + 2 * j2 + 1]);
    } else if (t < 72) {                              // gw2 (8,2): pair = both logits
        int k = t - 64;
        ws[t] = cvt2(gw2[k * 2 + 0], gw2[k * 2 + 1]);
    } else if (t < 76) {                              // gb1 (8)
        int j2 = t - 72;
        ws[t] = cvt2(gb1[2 * j2], gb1[2 * j2 + 1]);
    } else if (t < 268) {                             // e1w1 (16,24)
        int e = t - 76, k = e / 12, j2 = e % 12;
        ws[t] = cvt2(e1w1[k * 24 + 2 * j2], e1w1[k * 24 + 2 * j2 + 1]);
    } else if (t < 460) {                             // e1w2 (24,16)
        int e = t - 268, k = e >> 3, j2 = e & 7;
        ws[t] = cvt2(e1w2[k * 16 + 2 * j2], e1w2[k * 16 + 2 * j2 + 1]);
    } else if (t < 472) {                             // e1b1 (24)
        int j2 = t - 460;
        ws[t] = cvt2(e1b1[2 * j2], e1b1[2 * j2 + 1]);
    } else if (t < 480) {                             // e1b2 (16)
        int j2 = t - 472;
        ws[t] = cvt2(e1b2[2 * j2], e1b2[2 * j2 + 1]);
    } else if (t < 672) {                             // e2w1
        int e = t - 480, k = e / 12, j2 = e % 12;
        ws[t] = cvt2(e2w1[k * 24 + 2 * j2], e2w1[k * 24 + 2 * j2 + 1]);
    } else if (t < 864) {                             // e2w2
        int e = t - 672, k = e >> 3, j2 = e & 7;
        ws[t] = cvt2(e2w2[k * 16 + 2 * j2], e2w2[k * 16 + 2 * j2 + 1]);
    } else if (t < 876) {                             // e2b1
        int j2 = t - 864;
        ws[t] = cvt2(e2b1[2 * j2], e2b1[2 * j2 + 1]);
    } else if (t < 884) {                             // e2b2
        int j2 = t - 876;
        ws[t] = cvt2(e2b2[2 * j2], e2b2[2 * j2 + 1]);
    } else if (t < 1012) {                            // tw (16,16)
        int e = t - 884, k = e >> 3, j2 = e & 7;
        ws[t] = cvt2(tw[k * 16 + 2 * j2], tw[k * 16 + 2 * j2 + 1]);
    } else if (t < 1020) {                            // tb (16)
        int j2 = t - 1012;
        ws[t] = cvt2(tb[2 * j2], tb[2 * j2 + 1]);
    }
}

// One expert. xh[k] = splat(x_k) as hv2. acc (+)= scale * silu(h@w2+b2), fp32.
template <bool FIRST>
__device__ __forceinline__ void expert_pk16(const hv2 xh[16],
                                            const hv2* __restrict__ w1p,   // [16][12]
                                            const hv2* __restrict__ b1p,   // [12]
                                            const hv2* __restrict__ w2p,   // [24][8]
                                            const hv2* __restrict__ b2p,   // [8]
                                            const float* __restrict__ g,
                                            const float* __restrict__ bn,
                                            float scale, float* __restrict__ acc) {
    // ---- layer 1: hh[12] (packed pairs), fp16 accum ----
    hv2 hh[12];
#pragma unroll
    for (int j2 = 0; j2 < 12; ++j2) hh[j2] = b1p[j2];
#pragma unroll
    for (int k = 0; k < 16; ++k)
#pragma unroll
        for (int j2 = 0; j2 < 12; ++j2)
            hh[j2] = pkfma(xh[k], w1p[k * 12 + j2], hh[j2]);

    // ---- LN stats (unpack pass 1) ----
    float E = 0.0f, E2 = 0.0f;
#pragma unroll
    for (int j2 = 0; j2 < 12; ++j2) {
        float a = (float)hh[j2].x, b = (float)hh[j2].y;
        E += a + b;
        E2 = fmaf(a, a, fmaf(b, b, E2));
    }
    float mu = E * (1.0f / 24.0f);
    float var = fmaf(E2, 1.0f / 24.0f, -mu * mu);
    float rstd = rsqrtf(var + LN_EPS);

    // ---- norm + silu (unpack pass 2) -> splat regs for layer 2 ----
    hv2 hs[24];
#pragma unroll
    for (int j2 = 0; j2 < 12; ++j2) {
        float a = (float)hh[j2].x, b = (float)hh[j2].y;
        float n0 = fmaf((a - mu) * rstd, g[2 * j2], bn[2 * j2]);
        float n1 = fmaf((b - mu) * rstd, g[2 * j2 + 1], bn[2 * j2 + 1]);
        float s0 = silu_f(n0), s1 = silu_f(n1);
        hs[2 * j2 + 0] = cvt2(s0, s0);
        hs[2 * j2 + 1] = cvt2(s1, s1);
    }

    // ---- layer 2: ov[8] packed pairs ----
    hv2 ov[8];
#pragma unroll
    for (int j2 = 0; j2 < 8; ++j2) ov[j2] = b2p[j2];
#pragma unroll
    for (int k = 0; k < 24; ++k)
#pragma unroll
        for (int j2 = 0; j2 < 8; ++j2)
            ov[j2] = pkfma(hs[k], w2p[k * 8 + j2], ov[j2]);

#pragma unroll
    for (int j2 = 0; j2 < 8; ++j2) {
        float s0 = silu_f((float)ov[j2].x);
        float s1 = silu_f((float)ov[j2].y);
        if (FIRST) {
            acc[2 * j2 + 0] = scale * s0;
            acc[2 * j2 + 1] = scale * s1;
        } else {
            acc[2 * j2 + 0] = fmaf(scale, s0, acc[2 * j2 + 0]);
            acc[2 * j2 + 1] = fmaf(scale, s1, acc[2 * j2 + 1]);
        }
    }
}

__global__ __launch_bounds__(256) void moe_fused_kernel(
    const float* __restrict__ x,
    const hv2* __restrict__ ws,
    const float* __restrict__ gb2,
    const float* __restrict__ e1g, const float* __restrict__ e1bn,
    const float* __restrict__ e2g, const float* __restrict__ e2bn,
    const float* __restrict__ sw, const float* __restrict__ sb,
    const float* __restrict__ hw, const float* __restrict__ hb,
    float* __restrict__ out, int nrows) {
    int row = blockIdx.x * blockDim.x + threadIdx.x;
    if (row >= nrows) return;

    const hv2* gw1p  = ws;
    const hv2* gw2p  = ws + 64;
    const hv2* gb1p  = ws + 72;
    const hv2* e1w1p = ws + 76;
    const hv2* e1w2p = ws + 268;
    const hv2* e1b1p = ws + 460;
    const hv2* e1b2p = ws + 472;
    const hv2* e2w1p = ws + 480;
    const hv2* e2w2p = ws + 672;
    const hv2* e2b1p = ws + 864;
    const hv2* e2b2p = ws + 876;
    const hv2* twp   = ws + 884;
    const hv2* tbp   = ws + 1012;

    // ---- load x row; build splat-pair regs ----
    float xv[16];
    const float4* xr = reinterpret_cast<const float4*>(x + (size_t)row * 16);
#pragma unroll
    for (int i = 0; i < 4; ++i) {
        float4 v = xr[i];
        xv[4 * i + 0] = v.x;
        xv[4 * i + 1] = v.y;
        xv[4 * i + 2] = v.z;
        xv[4 * i + 3] = v.w;
    }
    hv2 xh[16];
#pragma unroll
    for (int k = 0; k < 16; ++k) xh[k] = cvt2(xv[k], xv[k]);

    // ---- gate ----
    hv2 ga[4];
#pragma unroll
    for (int j2 = 0; j2 < 4; ++j2) ga[j2] = gb1p[j2];
#pragma unroll
    for (int k = 0; k < 16; ++k)
#pragma unroll
        for (int j2 = 0; j2 < 4; ++j2)
            ga[j2] = pkfma(xh[k], gw1p[k * 4 + j2], ga[j2]);
    hv2 gl = cvt2(gb2[0], gb2[1]);
#pragma unroll
    for (int j2 = 0; j2 < 4; ++j2) {
        float t0 = tanh_f((float)ga[j2].x);
        float t1 = tanh_f((float)ga[j2].y);
        hv2 s0 = cvt2(t0, t0), s1 = cvt2(t1, t1);
        gl = pkfma(s0, gw2p[2 * j2 + 0], gl);
        gl = pkfma(s1, gw2p[2 * j2 + 1], gl);
    }
    float w0 = fast_rcp(1.0f + __expf((float)gl.y - (float)gl.x));   // sigmoid(l0-l1)
    float w1v = 1.0f - w0;

    // ---- experts (sequential; one expert's state live) ----
    float h[16];
    expert_pk16<true >(xh, e1w1p, e1b1p, e1w2p, e1b2p, e1g, e1bn, w0,  h);
    expert_pk16<false>(xh, e2w1p, e2b1p, e2w2p, e2b2p, e2g, e2bn, w1v, h);

    // ---- trunk: t = silu(h@tw + tb) ----
    hv2 hsp[16];
#pragma unroll
    for (int k = 0; k < 16; ++k) hsp[k] = cvt2(h[k], h[k]);
    hv2 tt[8];
#pragma unroll
    for (int j2 = 0; j2 < 8; ++j2) tt[j2] = tbp[j2];
#pragma unroll
    for (int k = 0; k < 16; ++k)
#pragma unroll
        for (int j2 = 0; j2 < 8; ++j2)
            tt[j2] = pkfma(hsp[k], twp[k * 8 + j2], tt[j2]);
    float t[16];
#pragma unroll
    for (int j2 = 0; j2 < 8; ++j2) {
        t[2 * j2 + 0] = silu_f((float)tt[j2].x);
        t[2 * j2 + 1] = silu_f((float)tt[j2].y);
    }

    // ---- heads (fp32) ----
    float strain = sb[0], hs0 = hb[0], hs1 = hb[1];
#pragma unroll
    for (int k = 0; k < 16; ++k) {
        strain = fmaf(t[k], sw[k], strain);
        hs0 = fmaf(t[k], hw[2 * k + 0], hs0);
        hs1 = fmaf(t[k], hw[2 * k + 1], hs1);
    }
    float gap = softplus_f(hs1);

    size_t o = (size_t)row * 3;
    out[o + 0] = strain;
    out[o + 1] = hs0;        // tensile_raw
    out[o + 2] = hs0 - gap;  // yield_strength
}

extern "C" void kernel_launch(void* const* d_in, const int* in_sizes, int n_in,
                              void* d_out, int out_size, void* d_ws, size_t ws_size,
                              hipStream_t stream) {
    const float* x    = (const float*)d_in[0];
    const float* gw1  = (const float*)d_in[1];
    const float* gb1  = (const float*)d_in[2];
    const float* gw2  = (const float*)d_in[3];
    const float* gb2  = (const float*)d_in[4];
    const float* e1w1 = (const float*)d_in[5];
    const float* e1b1 = (const float*)d_in[6];
    const float* e1g  = (const float*)d_in[7];
    const float* e1bn = (const float*)d_in[8];
    const float* e1w2 = (const float*)d_in[9];
    const float* e1b2 = (const float*)d_in[10];
    const float* e2w1 = (const float*)d_in[11];
    const float* e2b1 = (const float*)d_in[12];
    const float* e2g  = (const float*)d_in[13];
    const float* e2bn = (const float*)d_in[14];
    const float* e2w2 = (const float*)d_in[15];
    const float* e2b2 = (const float*)d_in[16];
    const float* tw   = (const float*)d_in[17];
    const float* tb   = (const float*)d_in[18];
    const float* sw   = (const float*)d_in[19];
    const float* sb   = (const float*)d_in[20];
    const float* hw   = (const float*)d_in[21];
    const float* hb   = (const float*)d_in[22];
    float* out = (float*)d_out;
    hv2* ws = (hv2*)d_ws;

    pack_weights<<<4, 256, 0, stream>>>(gw1, gb1, gw2, e1w1, e1b1, e1w2, e1b2,
                                        e2w1, e2b1, e2w2, e2b2, tw, tb, ws);

    int nrows = in_sizes[0] / 16;
    int block = 256;
    int grid = (nrows + block - 1) / block;
    moe_fused_kernel<<<grid, block, 0, stream>>>(
        x, ws, gb2, e1g, e1bn, e2g, e2bn, sw, sb, hw, hb, out, nrows);
}